// Round 6
// baseline (680.988 us; speedup 1.0000x reference)
//
#include <hip/hip_runtime.h>

// Stream compaction (R11): radix-shuffle restructure.
//   mask[i]  = accept_index[i] >= 0
//   dst[i]   = exclusive_prefix_sum(mask)[i]
//   out[dst[i]] = out_cache_loc[accept_index[i]]  for mask[i]
//   out[total..N) = 0
//
// R6-R10 established: the monolithic gather's pattern (8 non-coherent XCD L2s
// each randomly pulling the whole 64MB table) is rate-pegged at 3.65 TB/s x
// ~700MB FETCH (512MB = 8x64 XCD duplication). R11 removes the duplication:
//   histA: idx read #1, region histograms (64 x 1MB regions) + dst lookback
//   scan64/scan2: bucket offsets
//   binB:  idx read #2, write (dst,val) pairs bucketed by src region
//   gather: XCD-pinned regions (bid&7 -> XCD) -> each region gathered by ONE
//           XCD, L2-resident (~11 hits/line) -> src fetch 512MB -> ~64MB;
//           floats overwrite the val array sequentially
//   chunk: per-32K-slot output chunk, segments via blockBase binary search,
//          LDS assembly, full-line NT writes (tail zeros free)
// Fallback: if ws_size < ~135MB, run the verified R9 single-pass kernel.

#define N_TOTAL  16777216
#define BLOCK    256
#define EPT      16
#define TILE     (BLOCK * EPT)         // 4096
#define NB       (N_TOTAL / TILE)      // 4096 tiles

#define NR       64                    // src regions (1MB each)
#define REG_LG   18                    // region = v >> 18
#define CSTR     4100                  // cnt row stride (ints), 16B-aligned

#define CHUNK_LG 15
#define CHUNK    (1 << CHUNK_LG)       // 32768 out slots per chunk
#define NCH      (N_TOTAL / CHUNK)     // 512

// fallback (R9) gather tiling
#define SLICE_LG 20
#define SLICES   (N_TOTAL >> SLICE_LG) // 16

// workspace layout (bytes)
#define OFF_STATE 0ull
#define OFF_DST   32768ull
#define OFF_VAL   (OFF_DST + 4ull * N_TOTAL)
#define OFF_BB    (OFF_VAL + 4ull * N_TOTAL)
#define OFF_CNT   (OFF_BB + 16400ull)            // blockBase[4097] padded
#define OFF_RB    (OFF_CNT + 4ull * NR * CSTR)
#define WS_NEED   (OFF_RB + 4ull * (NR + 1))     // ~135.3 MB

typedef float vfloat4 __attribute__((ext_vector_type(4)));
typedef int   vint4   __attribute__((ext_vector_type(4)));

// ---------------- zero the lookback state ----------------
__global__ __launch_bounds__(256) void k_init(unsigned long long* __restrict__ state) {
    state[blockIdx.x * 256 + threadIdx.x] = 0ULL;
}

// ---------------- pass 1: histograms + dst lookback ----------------
__global__ __launch_bounds__(BLOCK) void k_histA(const int* __restrict__ idx,
                                                 unsigned long long* __restrict__ state,
                                                 int* __restrict__ blockBase,
                                                 int* __restrict__ cntArr) {
    const int b = blockIdx.x;
    const int t = threadIdx.x;
    const int lane = t & 63, wave = t >> 6;

    __shared__ int hist[NR];
    __shared__ int wsum[BLOCK / 64], woff[BLOCK / 64], btotal;
    __shared__ long long sBase;
    for (int r = t; r < NR; r += BLOCK) hist[r] = 0;

    const vint4* p = (const vint4*)(idx + (size_t)b * TILE + (size_t)t * EPT);
    int v[EPT];
#pragma unroll
    for (int j = 0; j < EPT / 4; ++j) {
        vint4 q = __builtin_nontemporal_load(p + j);
        v[4 * j + 0] = q.x; v[4 * j + 1] = q.y;
        v[4 * j + 2] = q.z; v[4 * j + 3] = q.w;
    }
    int ca = 0;
#pragma unroll
    for (int j = 0; j < EPT; ++j) ca += (v[j] >= 0);

    int x = ca;
#pragma unroll
    for (int d = 1; d < 64; d <<= 1) {
        int y = __shfl_up(x, d);
        if (lane >= d) x += y;
    }
    if (lane == 63) wsum[wave] = x;
    __syncthreads();
    if (t == 0) {
        int s = 0;
#pragma unroll
        for (int w = 0; w < BLOCK / 64; ++w) { woff[w] = s; s += wsum[w]; }
        btotal = s;
        if (b == 0) {
            __hip_atomic_store(&state[0], ((unsigned long long)s << 2) | 2ULL,
                               __ATOMIC_RELAXED, __HIP_MEMORY_SCOPE_AGENT);
            sBase = 0;
        } else {
            __hip_atomic_store(&state[b], ((unsigned long long)s << 2) | 1ULL,
                               __ATOMIC_RELAXED, __HIP_MEMORY_SCOPE_AGENT);
        }
    }
    __syncthreads();

#pragma unroll
    for (int j = 0; j < EPT; ++j)
        if (v[j] >= 0) atomicAdd(&hist[v[j] >> REG_LG], 1);
    __syncthreads();
    if (t < NR) cntArr[t * CSTR + b] = hist[t];

    // decoupled lookback (verbatim-proven)
    if (b > 0 && wave == 0) {
        long long excl = 0;
        int look = b - 1;
        for (;;) {
            const int pos = look - lane;
            unsigned long long s = 2ULL;
            if (pos >= 0)
                s = __hip_atomic_load(&state[pos], __ATOMIC_RELAXED,
                                      __HIP_MEMORY_SCOPE_AGENT);
            for (;;) {
                const bool need = (pos >= 0) && ((s & 3ULL) == 0ULL);
                if (!__any(need)) break;
                if (need) {
                    __builtin_amdgcn_s_sleep(2);
                    s = __hip_atomic_load(&state[pos], __ATOMIC_RELAXED,
                                          __HIP_MEMORY_SCOPE_AGENT);
                }
            }
            const unsigned long long ball = __ballot((s & 3ULL) == 2ULL);
            const int fp = ball ? (__ffsll((long long)ball) - 1) : 64;
            long long c = (lane <= fp) ? (long long)(s >> 2) : 0;
#pragma unroll
            for (int d = 32; d; d >>= 1) c += __shfl_down(c, d);
            excl += __shfl(c, 0);
            if (ball) break;
            look -= 64;
        }
        if (lane == 0) {
            __hip_atomic_store(&state[b],
                               (((unsigned long long)(excl + btotal)) << 2) | 2ULL,
                               __ATOMIC_RELAXED, __HIP_MEMORY_SCOPE_AGENT);
            sBase = excl;
        }
    }
    __syncthreads();
    if (t == 0) blockBase[b] = (int)(b == 0 ? 0 : sBase);
}

// ---------------- pass 2a: per-region exclusive scan over blocks ----------------
__global__ __launch_bounds__(256) void k_scan64(int* __restrict__ cntArr) {
    const int r = blockIdx.x, t = threadIdx.x;
    const int lane = t & 63, wave = t >> 6;
    int* row = cntArr + r * CSTR;
    int vals[16];
    const vint4* p = (const vint4*)(row + t * 16);
#pragma unroll
    for (int j = 0; j < 4; ++j) {
        vint4 q = p[j];
        vals[4 * j + 0] = q.x; vals[4 * j + 1] = q.y;
        vals[4 * j + 2] = q.z; vals[4 * j + 3] = q.w;
    }
    int tsum = 0;
#pragma unroll
    for (int j = 0; j < 16; ++j) tsum += vals[j];
    int x = tsum;
#pragma unroll
    for (int d = 1; d < 64; d <<= 1) {
        int y = __shfl_up(x, d);
        if (lane >= d) x += y;
    }
    __shared__ int wsum[4], woff[4];
    if (lane == 63) wsum[wave] = x;
    __syncthreads();
    if (t == 0) {
        int s = 0;
#pragma unroll
        for (int w = 0; w < 4; ++w) { woff[w] = s; s += wsum[w]; }
        row[4096] = s;                 // region total (sentinel)
    }
    __syncthreads();
    int run = (x - tsum) + woff[wave];
#pragma unroll
    for (int j = 0; j < 16; ++j) {
        row[t * 16 + j] = run;
        run += vals[j];
    }
}

// ---------------- pass 2b: scan of 64 region totals ----------------
__global__ __launch_bounds__(64) void k_scan2(const int* __restrict__ cntArr,
                                              int* __restrict__ regionBase,
                                              int* __restrict__ blockBase) {
    const int t = threadIdx.x;
    int x = cntArr[t * CSTR + 4096];
    int incl = x;
#pragma unroll
    for (int d = 1; d < 64; d <<= 1) {
        int y = __shfl_up(incl, d);
        if (t >= d) incl += y;
    }
    regionBase[t] = incl - x;
    if (t == 63) { regionBase[64] = incl; blockBase[4096] = incl; }
}

// ---------------- pass 3: bin (dst,val) pairs by src region ----------------
__global__ __launch_bounds__(BLOCK) void k_binB(const int* __restrict__ idx,
                                                const int* __restrict__ blockBase,
                                                const int* __restrict__ cntArr,
                                                const int* __restrict__ regionBase,
                                                int* __restrict__ dstArr,
                                                int* __restrict__ valArr) {
    const int b = blockIdx.x;
    const int t = threadIdx.x;
    const int lane = t & 63, wave = t >> 6;

    __shared__ int hist[NR], rscan[NR + 1], rcnt[NR], sG[NR];
    __shared__ int ldsD[TILE], ldsV[TILE];
    __shared__ int wsum[BLOCK / 64], woff[BLOCK / 64], btotal;
    for (int r = t; r < NR; r += BLOCK) { hist[r] = 0; rcnt[r] = 0; }

    const vint4* p = (const vint4*)(idx + (size_t)b * TILE + (size_t)t * EPT);
    int v[EPT];
#pragma unroll
    for (int j = 0; j < EPT / 4; ++j) {
        vint4 q = __builtin_nontemporal_load(p + j);
        v[4 * j + 0] = q.x; v[4 * j + 1] = q.y;
        v[4 * j + 2] = q.z; v[4 * j + 3] = q.w;
    }
    int ca = 0;
#pragma unroll
    for (int j = 0; j < EPT; ++j) ca += (v[j] >= 0);

    int x = ca;
#pragma unroll
    for (int d = 1; d < 64; d <<= 1) {
        int y = __shfl_up(x, d);
        if (lane >= d) x += y;
    }
    if (lane == 63) wsum[wave] = x;
    __syncthreads();
    if (t == 0) {
        int s = 0;
#pragma unroll
        for (int w = 0; w < BLOCK / 64; ++w) { woff[w] = s; s += wsum[w]; }
        btotal = s;
    }
    __syncthreads();
    const int off0 = (x - ca) + woff[wave];
    const int base = blockBase[b];

#pragma unroll
    for (int j = 0; j < EPT; ++j)
        if (v[j] >= 0) atomicAdd(&hist[v[j] >> REG_LG], 1);
    __syncthreads();
    if (t == 0) {
        int s = 0;
#pragma unroll
        for (int r = 0; r < NR; ++r) { rscan[r] = s; s += hist[r]; }
        rscan[NR] = s;
    }
    if (t < NR) sG[t] = regionBase[t] + cntArr[t * CSTR + b];
    __syncthreads();

    int o = off0;
#pragma unroll
    for (int j = 0; j < EPT; ++j) {
        if (v[j] >= 0) {
            const int r = v[j] >> REG_LG;
            const int pos = rscan[r] + atomicAdd(&rcnt[r], 1);
            ldsD[pos] = base + o;
            ldsV[pos] = v[j];
            ++o;
        }
    }
    __syncthreads();

    const int tot = btotal;
    for (int i = t; i < tot; i += BLOCK) {
        int loR = 0, hiR = NR;          // find r: rscan[r] <= i < rscan[r+1]
        while (hiR - loR > 1) {
            const int mid = (loR + hiR) >> 1;
            if (rscan[mid] <= i) loR = mid; else hiR = mid;
        }
        const int g = sG[loR] + (i - rscan[loR]);
        dstArr[g] = ldsD[i];
        valArr[g] = ldsV[i];
    }
}

// ---------------- pass 4: XCD-pinned region gather (in-place int->float) ----------------
__global__ __launch_bounds__(BLOCK) void k_gather(const float* __restrict__ src,
                                                  const int* __restrict__ cntArr,
                                                  const int* __restrict__ regionBase,
                                                  int* __restrict__ valArr) {
    const int b = blockIdx.x, t = threadIdx.x;
    const int xcd = b & 7, w = b >> 3;          // bid round-robins XCDs (m09)
#pragma unroll 1
    for (int ti = 0; ti < 8; ++ti) {
        const int r = xcd * 8 + ti;             // XCD x owns regions [8x,8x+8)
        const int tot = cntArr[r * CSTR + 4096];
        const int rb = regionBase[r];
        const int per = (tot + 255) >> 8;       // 256 blocks per XCD
        const int s0 = w * per;
        const int s1 = (s0 + per < tot) ? s0 + per : tot;
        int i = s0 + t;
        for (; i + 3 * BLOCK < s1; i += 4 * BLOCK) {
            const int a0 = __builtin_nontemporal_load(valArr + rb + i);
            const int a1 = __builtin_nontemporal_load(valArr + rb + i + BLOCK);
            const int a2 = __builtin_nontemporal_load(valArr + rb + i + 2 * BLOCK);
            const int a3 = __builtin_nontemporal_load(valArr + rb + i + 3 * BLOCK);
            const float f0 = src[a0], f1 = src[a1], f2 = src[a2], f3 = src[a3];
            __builtin_nontemporal_store(__float_as_int(f0), valArr + rb + i);
            __builtin_nontemporal_store(__float_as_int(f1), valArr + rb + i + BLOCK);
            __builtin_nontemporal_store(__float_as_int(f2), valArr + rb + i + 2 * BLOCK);
            __builtin_nontemporal_store(__float_as_int(f3), valArr + rb + i + 3 * BLOCK);
        }
        for (; i < s1; i += BLOCK) {
            const int a = __builtin_nontemporal_load(valArr + rb + i);
            __builtin_nontemporal_store(__float_as_int(src[a]), valArr + rb + i);
        }
    }
}

// ---------------- pass 5: per-chunk assembly + full-line NT writes ----------------
__global__ __launch_bounds__(BLOCK) void k_chunk(const int* __restrict__ blockBase,
                                                 const int* __restrict__ cntArr,
                                                 const int* __restrict__ regionBase,
                                                 const int* __restrict__ dstArr,
                                                 const int* __restrict__ valArr,
                                                 float* __restrict__ out) {
    const int m = blockIdx.x, t = threadIdx.x;
    const int lo = m << CHUNK_LG, hi = lo + CHUNK;
    __shared__ int buf[CHUNK];                  // 128 KB
    __shared__ int sblo, sbhi;
    __shared__ int segA[NR], segB[NR], segC[NR], segD[NR];

    for (int i = t * 4; i < CHUNK; i += BLOCK * 4)
        *(vint4*)(buf + i) = (vint4)(0);

    if (t == 0) {
        int a = 0, c = NB - 1;                  // blo: max b with blockBase[b] <= lo
        while (a < c) { const int mid = (a + c + 1) >> 1;
                        if (blockBase[mid] <= lo) a = mid; else c = mid - 1; }
        sblo = a;
        a = 0; c = NB - 1;                      // bhi: max b with blockBase[b] < hi
        while (a < c) { const int mid = (a + c + 1) >> 1;
                        if (blockBase[mid] < hi) a = mid; else c = mid - 1; }
        sbhi = a;
    }
    __syncthreads();
    const int blo = sblo, bhi = sbhi;
    if (t < NR) {
        segA[t] = regionBase[t] + cntArr[t * CSTR + blo];
        segB[t] = regionBase[t] + cntArr[t * CSTR + blo + 1];
        segC[t] = regionBase[t] + cntArr[t * CSTR + bhi];
        segD[t] = regionBase[t] + cntArr[t * CSTR + bhi + 1];
    }
    __syncthreads();

#pragma unroll 1
    for (int r = 0; r < NR; ++r) {
        // whole blocks strictly inside (lo,hi): unconditional
        for (int j = segB[r] + t; j < segC[r]; j += BLOCK)
            buf[__builtin_nontemporal_load(dstArr + j) - lo] =
                __builtin_nontemporal_load(valArr + j);
        // boundary block blo: filter
        for (int j = segA[r] + t; j < segB[r]; j += BLOCK) {
            const int d = __builtin_nontemporal_load(dstArr + j);
            if (d >= lo && d < hi)
                buf[d - lo] = __builtin_nontemporal_load(valArr + j);
        }
        // boundary block bhi (if distinct): filter
        if (bhi != blo)
            for (int j = segC[r] + t; j < segD[r]; j += BLOCK) {
                const int d = __builtin_nontemporal_load(dstArr + j);
                if (d >= lo && d < hi)
                    buf[d - lo] = __builtin_nontemporal_load(valArr + j);
            }
    }
    __syncthreads();

    for (int i = t * 4; i < CHUNK; i += BLOCK * 4) {
        vfloat4 q = { __int_as_float(buf[i]), __int_as_float(buf[i + 1]),
                      __int_as_float(buf[i + 2]), __int_as_float(buf[i + 3]) };
        __builtin_nontemporal_store(q, (vfloat4*)(out + lo + i));
    }
}

// ================= fallback: verified R9 single-pass kernel =================
__global__ __launch_bounds__(BLOCK, 8) void fb_compact(const int* __restrict__ idx,
                                                       const float* __restrict__ src,
                                                       float* __restrict__ out,
                                                       unsigned long long* __restrict__ state) {
    const int b = blockIdx.x;
    const int t = threadIdx.x;
    const int lane = t & 63, wave = t >> 6;

    __shared__ int wsum[BLOCK / 64], woff[BLOCK / 64], btotal;
    __shared__ long long sBase;
    __shared__ float vals[TILE];

    const vint4* p = (const vint4*)(idx + (size_t)b * TILE + (size_t)t * EPT);
    int v[EPT];
#pragma unroll
    for (int j = 0; j < EPT / 4; ++j) {
        vint4 q = __builtin_nontemporal_load(p + j);
        v[4 * j + 0] = q.x; v[4 * j + 1] = q.y;
        v[4 * j + 2] = q.z; v[4 * j + 3] = q.w;
    }
    int ca = 0;
#pragma unroll
    for (int j = 0; j < EPT; ++j) ca += (v[j] >= 0);

    int x = ca;
#pragma unroll
    for (int d = 1; d < 64; d <<= 1) {
        int y = __shfl_up(x, d);
        if (lane >= d) x += y;
    }
    if (lane == 63) wsum[wave] = x;
    __syncthreads();
    if (t == 0) {
        int s = 0;
#pragma unroll
        for (int w = 0; w < BLOCK / 64; ++w) { woff[w] = s; s += wsum[w]; }
        btotal = s;
        if (b == 0) {
            __hip_atomic_store(&state[0], ((unsigned long long)s << 2) | 2ULL,
                               __ATOMIC_RELAXED, __HIP_MEMORY_SCOPE_AGENT);
            sBase = 0;
        } else {
            __hip_atomic_store(&state[b], ((unsigned long long)s << 2) | 1ULL,
                               __ATOMIC_RELAXED, __HIP_MEMORY_SCOPE_AGENT);
        }
    }
    __syncthreads();

    const int off0 = (x - ca) + woff[wave];
#pragma unroll 1
    for (int s = 0; s < SLICES; ++s) {
        float tmp[EPT];
#pragma unroll
        for (int j = 0; j < EPT; ++j) {
            const bool m = (int)((unsigned)v[j] >> SLICE_LG) == s;
            tmp[j] = src[m ? v[j] : 0];
        }
        asm volatile("s_waitcnt vmcnt(0)" ::: "memory");
        int o = off0;
#pragma unroll
        for (int j = 0; j < EPT; ++j) {
            const bool acc = v[j] >= 0;
            const bool m = (int)((unsigned)v[j] >> SLICE_LG) == s;
            if (m) vals[o] = tmp[j];
            o += acc;
        }
    }

    if (b > 0 && wave == 0) {
        long long excl = 0;
        int look = b - 1;
        for (;;) {
            const int pos = look - lane;
            unsigned long long s = 2ULL;
            if (pos >= 0)
                s = __hip_atomic_load(&state[pos], __ATOMIC_RELAXED,
                                      __HIP_MEMORY_SCOPE_AGENT);
            for (;;) {
                const bool need = (pos >= 0) && ((s & 3ULL) == 0ULL);
                if (!__any(need)) break;
                if (need) {
                    __builtin_amdgcn_s_sleep(2);
                    s = __hip_atomic_load(&state[pos], __ATOMIC_RELAXED,
                                          __HIP_MEMORY_SCOPE_AGENT);
                }
            }
            const unsigned long long ball = __ballot((s & 3ULL) == 2ULL);
            const int fp = ball ? (__ffsll((long long)ball) - 1) : 64;
            long long c = (lane <= fp) ? (long long)(s >> 2) : 0;
#pragma unroll
            for (int d = 32; d; d >>= 1) c += __shfl_down(c, d);
            excl += __shfl(c, 0);
            if (ball) break;
            look -= 64;
        }
        if (lane == 0) {
            __hip_atomic_store(&state[b],
                               (((unsigned long long)(excl + btotal)) << 2) | 2ULL,
                               __ATOMIC_RELAXED, __HIP_MEMORY_SCOPE_AGENT);
            sBase = excl;
        }
    }
    __syncthreads();

    const int tot = btotal;
    const long long base = sBase;
    {
        const long long gbeg = base, gend = base + tot;
        const long long a0 = (gbeg + 3) & ~3LL;
        const long long a1 = gend & ~3LL;
        const long long hend = a0 < gend ? a0 : gend;
        for (long long g = gbeg + t; g < hend; g += BLOCK)
            __builtin_nontemporal_store(vals[(int)(g - gbeg)], out + g);
        if (a0 < gend) {
            for (long long g = a0 + (long long)t * 4; g < a1; g += (long long)BLOCK * 4) {
                const int l = (int)(g - gbeg);
                vfloat4 w = { vals[l], vals[l + 1], vals[l + 2], vals[l + 3] };
                __builtin_nontemporal_store(w, (vfloat4*)(out + g));
            }
            for (long long g = a1 + t; g < gend; g += BLOCK)
                __builtin_nontemporal_store(vals[(int)(g - gbeg)], out + g);
        }
    }
    {
        const long long rprev = (long long)b * TILE - base;
        const int rcnt2 = TILE - tot;
        const long long zbeg = (long long)N_TOTAL - rprev - rcnt2;
        const long long zend = (long long)N_TOTAL - rprev;
        const long long a0 = (zbeg + 3) & ~3LL;
        const long long a1 = zend & ~3LL;
        const long long hend = a0 < zend ? a0 : zend;
        for (long long g = zbeg + t; g < hend; g += BLOCK)
            __builtin_nontemporal_store(0.0f, out + g);
        if (a0 < zend) {
            const vfloat4 z = (vfloat4)(0.f);
            for (long long g = a0 + (long long)t * 4; g < a1; g += (long long)BLOCK * 4)
                __builtin_nontemporal_store(z, (vfloat4*)(out + g));
            for (long long g = a1 + t; g < zend; g += BLOCK)
                __builtin_nontemporal_store(0.0f, out + g);
        }
    }
}

extern "C" void kernel_launch(void* const* d_in, const int* in_sizes, int n_in,
                              void* d_out, int out_size, void* d_ws, size_t ws_size,
                              hipStream_t stream) {
    const int*   idx = (const int*)d_in[0];     // accept_index (int32 per harness)
    const float* src = (const float*)d_in[1];   // out_cache_loc
    float*       out = (float*)d_out;

    char* w = (char*)d_ws;
    unsigned long long* state = (unsigned long long*)(w + OFF_STATE);

    if (ws_size >= WS_NEED) {
        int* dstArr     = (int*)(w + OFF_DST);
        int* valArr     = (int*)(w + OFF_VAL);
        int* blockBase  = (int*)(w + OFF_BB);
        int* cntArr     = (int*)(w + OFF_CNT);
        int* regionBase = (int*)(w + OFF_RB);

        k_init  <<<16, 256, 0, stream>>>(state);
        k_histA <<<NB, BLOCK, 0, stream>>>(idx, state, blockBase, cntArr);
        k_scan64<<<NR, 256, 0, stream>>>(cntArr);
        k_scan2 <<<1, 64, 0, stream>>>(cntArr, regionBase, blockBase);
        k_binB  <<<NB, BLOCK, 0, stream>>>(idx, blockBase, cntArr, regionBase,
                                           dstArr, valArr);
        k_gather<<<2048, BLOCK, 0, stream>>>(src, cntArr, regionBase, valArr);
        k_chunk <<<NCH, BLOCK, 0, stream>>>(blockBase, cntArr, regionBase,
                                            dstArr, valArr, out);
    } else {
        k_init    <<<16, 256, 0, stream>>>(state);
        fb_compact<<<NB, BLOCK, 0, stream>>>(idx, src, out, state);
    }
}

// Round 7
// 329.785 us; speedup vs baseline: 2.0649x; 2.0649x over previous
//
#include <hip/hip_runtime.h>

// Stream compaction, single fused pass (R12 = consolidated best):
//   mask[i]  = accept_index[i] >= 0
//   dst[i]   = exclusive_prefix_sum(mask)[i]
//   out[dst[i]] = out_cache_loc[accept_index[i]]  for mask[i]
//   out[total..N) = 0
//
// Evidence ledger (R4-R11):
//  - random-gather service rate pegged at 3.65 TB/s regardless of occupancy
//    (30-72%), slice size (4-16MB), persistence, MLP depth; NT gather loads
//    REGRESS (2.5 TB/s: L2 same-line merging is load-bearing).
//  - cross-XCD dedup unreachable: phase-locked slices need <=1.3MB (issue-
//    bound) or grid barriers (cost >= savings); pair round-trip (R11) = 2x
//    WORSE (pass overhead + 1-block/CU chunk assembly).
//  => kernel floor = ~755MB @ 3.65 TB/s ~= 207us. This version consolidates
//     the best measured config: EPT2=32, 4x16MB slices, 2048 blocks (R6,
//     212us) + NT idx loads, post-sweep lookback, float4-peel NT stores (R9).

#define N_TOTAL  16777216
#define BLOCK    256

#define EPT2     32
#define TILE2    (BLOCK * EPT2)        // 8192
#define NB2      (N_TOTAL / TILE2)     // 2048

#define SLICE_LG 22                    // 2^22 elements = 16 MB per slice
#define SLICES   (N_TOTAL >> SLICE_LG) // 4

typedef float vfloat4 __attribute__((ext_vector_type(4)));
typedef int   vint4   __attribute__((ext_vector_type(4)));

// ---------------- pass 0: zero the lookback state (16 KB) ----------------
__global__ __launch_bounds__(256) void k_init(unsigned long long* __restrict__ state) {
    state[blockIdx.x * 256 + threadIdx.x] = 0ULL;
}

// ---------------- single fused pass ----------------
__global__ __launch_bounds__(BLOCK) void k_compact(const int* __restrict__ idx,
                                                   const float* __restrict__ src,
                                                   float* __restrict__ out,
                                                   unsigned long long* __restrict__ state) {
    const int b = blockIdx.x;
    const int t = threadIdx.x;
    const int lane = t & 63, wave = t >> 6;

    __shared__ int wsum[BLOCK / 64], woff[BLOCK / 64], btotal;
    __shared__ long long sBase;
    __shared__ float vals[TILE2];

    // ---- load idx tile (NT: read-once; only read of accept_index) ----
    const vint4* p = (const vint4*)(idx + (size_t)b * TILE2 + (size_t)t * EPT2);
    int v[EPT2];
#pragma unroll
    for (int j = 0; j < EPT2 / 4; ++j) {
        vint4 q = __builtin_nontemporal_load(p + j);
        v[4 * j + 0] = q.x; v[4 * j + 1] = q.y;
        v[4 * j + 2] = q.z; v[4 * j + 3] = q.w;
    }
    int cnt = 0;
#pragma unroll
    for (int j = 0; j < EPT2; ++j) cnt += (v[j] >= 0);

    // ---- block exclusive scan of per-thread counts ----
    int x = cnt;
#pragma unroll
    for (int d = 1; d < 64; d <<= 1) {
        int y = __shfl_up(x, d);
        if (lane >= d) x += y;
    }
    if (lane == 63) wsum[wave] = x;
    __syncthreads();
    if (t == 0) {
        int s = 0;
#pragma unroll
        for (int w = 0; w < BLOCK / 64; ++w) { woff[w] = s; s += wsum[w]; }
        btotal = s;
        if (b == 0) {
            // flag 2 = PREFIX (inclusive), value in bits [2..]
            __hip_atomic_store(&state[0], ((unsigned long long)s << 2) | 2ULL,
                               __ATOMIC_RELAXED, __HIP_MEMORY_SCOPE_AGENT);
            sBase = 0;
        } else {
            // flag 1 = PARTIAL -- published BEFORE the gather phase
            __hip_atomic_store(&state[b], ((unsigned long long)s << 2) | 1ULL,
                               __ATOMIC_RELAXED, __HIP_MEMORY_SCOPE_AGENT);
        }
    }
    __syncthreads();

    const int off0 = (x - cnt) + woff[wave];   // this thread's first LDS slot

    // ---- slice-swept batched gather -> LDS compact (R5/R6-proven core) ----
    // Per slice: 32 BRANCH-FREE loads (non-matching lanes read src[0], which
    // stays L1/L2-hot) -> one vmcnt(0) -> conditional LDS commit. Keeps ~8
    // real loads in flight per thread while preserving slice locality.
#pragma unroll 1
    for (int s = 0; s < SLICES; ++s) {
        float tmp[EPT2];
#pragma unroll
        for (int j = 0; j < EPT2; ++j) {
            const bool m = (int)((unsigned)v[j] >> SLICE_LG) == s;
            tmp[j] = src[m ? v[j] : 0];
        }
        asm volatile("s_waitcnt vmcnt(0)" ::: "memory");
        int o = off0;
#pragma unroll
        for (int j = 0; j < EPT2; ++j) {
            const bool acc = v[j] >= 0;
            const bool m = (int)((unsigned)v[j] >> SLICE_LG) == s;
            if (m) vals[o] = tmp[j];
            o += acc;
        }
    }

    // ---- decoupled lookback AFTER the sweep (off the critical path) ----
    if (b > 0 && wave == 0) {
        long long excl = 0;
        int look = b - 1;
        for (;;) {
            const int pos = look - lane;          // lane 0 = nearest predecessor
            unsigned long long s = 2ULL;          // pos<0 -> fake PREFIX(0)
            if (pos >= 0)
                s = __hip_atomic_load(&state[pos], __ATOMIC_RELAXED,
                                      __HIP_MEMORY_SCOPE_AGENT);
            for (;;) {
                const bool need = (pos >= 0) && ((s & 3ULL) == 0ULL);
                if (!__any(need)) break;
                if (need) {
                    __builtin_amdgcn_s_sleep(2);  // throttle spin traffic
                    s = __hip_atomic_load(&state[pos], __ATOMIC_RELAXED,
                                          __HIP_MEMORY_SCOPE_AGENT);
                }
            }
            const unsigned long long ball = __ballot((s & 3ULL) == 2ULL);
            const int fp = ball ? (__ffsll((long long)ball) - 1) : 64;
            long long c = (lane <= fp) ? (long long)(s >> 2) : 0;
#pragma unroll
            for (int d = 32; d; d >>= 1) c += __shfl_down(c, d);
            excl += __shfl(c, 0);
            if (ball) break;                      // found a PREFIX -> done
            look -= 64;                           // whole window PARTIAL
        }
        if (lane == 0) {
            __hip_atomic_store(&state[b],
                               (((unsigned long long)(excl + btotal)) << 2) | 2ULL,
                               __ATOMIC_RELAXED, __HIP_MEMORY_SCOPE_AGENT);
            sBase = excl;
        }
    }
    __syncthreads();

    const int tot = btotal;
    const long long base = sBase;          // global exclusive accept prefix

    // ---- data write [base, base+tot): float4 NT with alignment peel ----
    {
        const long long gbeg = base, gend = base + tot;
        const long long a0 = (gbeg + 3) & ~3LL;   // first 16B-aligned idx
        const long long a1 = gend & ~3LL;         // end of vector region
        const long long hend = a0 < gend ? a0 : gend;
        for (long long g = gbeg + t; g < hend; g += BLOCK)
            __builtin_nontemporal_store(vals[(int)(g - gbeg)], out + g);
        if (a0 < gend) {
            for (long long g = a0 + (long long)t * 4; g < a1; g += (long long)BLOCK * 4) {
                const int l = (int)(g - gbeg);
                vfloat4 w = { vals[l], vals[l + 1], vals[l + 2], vals[l + 3] };
                __builtin_nontemporal_store(w, (vfloat4*)(out + g));
            }
            for (long long g = a1 + t; g < gend; g += BLOCK)
                __builtin_nontemporal_store(vals[(int)(g - gbeg)], out + g);
        }
    }

    // ---- fused tail zero via reject-prefix identity ----
    // rejects before this block: r = b*TILE2 - base; this block owes
    // rcnt = TILE2 - tot zeros at [N - r - rcnt, N - r). Union over all
    // blocks = [total, N), disjoint, never overlaps data writes.
    {
        const long long rprev = (long long)b * TILE2 - base;
        const int rcnt = TILE2 - tot;
        const long long zbeg = (long long)N_TOTAL - rprev - rcnt;
        const long long zend = (long long)N_TOTAL - rprev;
        const long long a0 = (zbeg + 3) & ~3LL;
        const long long a1 = zend & ~3LL;
        const long long hend = a0 < zend ? a0 : zend;
        for (long long g = zbeg + t; g < hend; g += BLOCK)
            __builtin_nontemporal_store(0.0f, out + g);
        if (a0 < zend) {
            const vfloat4 z = (vfloat4)(0.f);
            for (long long g = a0 + (long long)t * 4; g < a1; g += (long long)BLOCK * 4)
                __builtin_nontemporal_store(z, (vfloat4*)(out + g));
            for (long long g = a1 + t; g < zend; g += BLOCK)
                __builtin_nontemporal_store(0.0f, out + g);
        }
    }
}

extern "C" void kernel_launch(void* const* d_in, const int* in_sizes, int n_in,
                              void* d_out, int out_size, void* d_ws, size_t ws_size,
                              hipStream_t stream) {
    const int*   idx = (const int*)d_in[0];     // accept_index (int32 per harness)
    const float* src = (const float*)d_in[1];   // out_cache_loc
    float*       out = (float*)d_out;

    unsigned long long* state = (unsigned long long*)d_ws;  // NB2 x u64 = 16 KB

    k_init   <<<NB2 / 256, 256, 0, stream>>>(state);
    k_compact<<<NB2, BLOCK, 0, stream>>>(idx, src, out, state);
}

// Round 8
// 322.126 us; speedup vs baseline: 2.1140x; 1.0238x over previous
//
#include <hip/hip_runtime.h>

// Stream compaction, single-pass (R13 = verbatim R6, the measured optimum):
//   mask[i]  = accept_index[i] >= 0
//   dst[i]   = exclusive_prefix_sum(mask)[i]
//   out[dst[i]] = out_cache_loc[accept_index[i]]  for mask[i]
//   out[total..N) = 0
//
// Evidence ledger (R4-R12):
//  - random-gather service rate pegged at 3.65-3.7 TB/s across occupancy
//    30-72%, slice 4-16MB, persistent/drifting, MLP 1-8; NT gather loads
//    REGRESS to 2.5 TB/s (L2 same-line merging is load-bearing).
//  - cross-XCD dedup unreachable: R11 pair-materialization = 2x worse.
//  - R12 A/B: NT idx loads = +25MB FETCH (sector-merge defeated); float4
//    LDS-read stores = 2.5x bank conflicts. Both reverted here.
//  => floor = ~758MB @ 3.65TB/s ~= 208us kernel; R6/R13 measures 212 (98%).
// Config: EPT2=32, 4x16MB slices, 2048 blocks, plain idx loads, pre-sweep
// PARTIAL publish + pre-write lookback, scalar NT stores.

#define N_TOTAL  16777216
#define BLOCK    256

#define EPT2     32
#define TILE2    (BLOCK * EPT2)        // 8192
#define NB2      (N_TOTAL / TILE2)     // 2048

#define SLICE_LG 22                    // 2^22 elements = 16 MB per slice
#define SLICES   (N_TOTAL >> SLICE_LG) // 4

typedef float vfloat4 __attribute__((ext_vector_type(4)));

// ---------------- pass 0: zero the lookback state (16 KB) ----------------
__global__ __launch_bounds__(256) void k_init(unsigned long long* __restrict__ state) {
    state[blockIdx.x * 256 + threadIdx.x] = 0ULL;
}

// ---------------- single fused pass ----------------
__global__ __launch_bounds__(BLOCK) void k_compact(const int* __restrict__ idx,
                                                   const float* __restrict__ src,
                                                   float* __restrict__ out,
                                                   unsigned long long* __restrict__ state) {
    const int b = blockIdx.x;
    const int t = threadIdx.x;
    const int lane = t & 63, wave = t >> 6;

    // ---- load idx tile (plain loads: NT variant costs +25MB FETCH, R12) ----
    const int4* p = (const int4*)(idx + (size_t)b * TILE2 + (size_t)t * EPT2);
    int v[EPT2];
#pragma unroll
    for (int j = 0; j < EPT2 / 4; ++j) {
        int4 q = p[j];
        v[4 * j + 0] = q.x; v[4 * j + 1] = q.y;
        v[4 * j + 2] = q.z; v[4 * j + 3] = q.w;
    }
    int cnt = 0;
#pragma unroll
    for (int j = 0; j < EPT2; ++j) cnt += (v[j] >= 0);

    // ---- block exclusive scan of per-thread counts ----
    int x = cnt;
#pragma unroll
    for (int d = 1; d < 64; d <<= 1) {
        int y = __shfl_up(x, d);
        if (lane >= d) x += y;
    }
    __shared__ int wsum[BLOCK / 64], woff[BLOCK / 64];
    __shared__ int btotal;
    __shared__ long long sBase;
    if (lane == 63) wsum[wave] = x;
    __syncthreads();
    if (t == 0) {
        int s = 0;
#pragma unroll
        for (int w = 0; w < BLOCK / 64; ++w) { woff[w] = s; s += wsum[w]; }
        btotal = s;
        if (b == 0) {
            // flag 2 = PREFIX (inclusive), value in bits [2..]
            __hip_atomic_store(&state[0], ((unsigned long long)s << 2) | 2ULL,
                               __ATOMIC_RELAXED, __HIP_MEMORY_SCOPE_AGENT);
            sBase = 0;
        } else {
            // flag 1 = PARTIAL (aggregate) -- published before the gather phase
            __hip_atomic_store(&state[b], ((unsigned long long)s << 2) | 1ULL,
                               __ATOMIC_RELAXED, __HIP_MEMORY_SCOPE_AGENT);
        }
    }

    // ---- decoupled lookback: wave 0, 64-wide windows ----
    if (b > 0 && wave == 0) {
        long long excl = 0;
        int look = b - 1;
        for (;;) {
            const int pos = look - lane;              // lane 0 = nearest predecessor
            unsigned long long s = 2ULL;              // pos<0 -> fake PREFIX(0)
            if (pos >= 0)
                s = __hip_atomic_load(&state[pos], __ATOMIC_RELAXED,
                                      __HIP_MEMORY_SCOPE_AGENT);
            for (;;) {
                const bool need = (pos >= 0) && ((s & 3ULL) == 0ULL);
                if (!__any(need)) break;
                if (need) {
                    __builtin_amdgcn_s_sleep(2);      // throttle spin traffic
                    s = __hip_atomic_load(&state[pos], __ATOMIC_RELAXED,
                                          __HIP_MEMORY_SCOPE_AGENT);
                }
            }
            const unsigned long long ball = __ballot((s & 3ULL) == 2ULL);
            const int fp = ball ? (__ffsll((long long)ball) - 1) : 64;
            long long c = (lane <= fp) ? (long long)(s >> 2) : 0; // fp==64 -> all
#pragma unroll
            for (int d = 32; d; d >>= 1) c += __shfl_down(c, d);
            excl += __shfl(c, 0);
            if (ball) break;                          // found a PREFIX -> done
            look -= 64;                               // whole window PARTIAL
        }
        if (lane == 0) {
            __hip_atomic_store(&state[b],
                               (((unsigned long long)(excl + btotal)) << 2) | 2ULL,
                               __ATOMIC_RELAXED, __HIP_MEMORY_SCOPE_AGENT);
            sBase = excl;
        }
    }
    __syncthreads();

    const int off0 = (x - cnt) + woff[wave];   // this thread's first LDS slot
    const int tot  = btotal;
    const long long base = sBase;              // global exclusive accept prefix

    // ---- slice-swept batched gather -> LDS compact ----
    // Per slice: 32 BRANCH-FREE loads (non-matching lanes read src[0], which
    // stays L1/L2-hot) -> one vmcnt(0) -> conditional LDS commit. Keeps ~8
    // real loads in flight per thread while preserving slice temporal
    // locality for L2/L3 reuse.
    __shared__ float vals[TILE2];
#pragma unroll 1
    for (int s = 0; s < SLICES; ++s) {
        float tmp[EPT2];
#pragma unroll
        for (int j = 0; j < EPT2; ++j) {
            const bool m = (int)((unsigned)v[j] >> SLICE_LG) == s;
            tmp[j] = src[m ? v[j] : 0];
        }
        asm volatile("s_waitcnt vmcnt(0)" ::: "memory");
        int o = off0;
#pragma unroll
        for (int j = 0; j < EPT2; ++j) {
            const bool acc = v[j] >= 0;
            const bool m = (int)((unsigned)v[j] >> SLICE_LG) == s;
            if (m) vals[o] = tmp[j];
            o += acc;
        }
    }
    __syncthreads();

    // ---- contiguous, fully-coalesced block write: [base, base+tot) ----
    for (int i = t; i < tot; i += BLOCK)
        __builtin_nontemporal_store(vals[i], out + base + i);

    // ---- fused tail zero via reject-prefix identity ----
    // rejects before this block: r = b*TILE2 - base; this block owes
    // rcnt = TILE2 - tot zeros at [N - r - rcnt, N - r). Union over all
    // blocks = [total, N), disjoint, never overlaps data writes.
    const long long rprev = (long long)b * TILE2 - base;
    const int rcnt = TILE2 - tot;
    float* zp = out + ((long long)N_TOTAL - rprev - rcnt);
    for (int i = t; i < rcnt; i += BLOCK)
        __builtin_nontemporal_store(0.0f, zp + i);
}

extern "C" void kernel_launch(void* const* d_in, const int* in_sizes, int n_in,
                              void* d_out, int out_size, void* d_ws, size_t ws_size,
                              hipStream_t stream) {
    const int*   idx = (const int*)d_in[0];     // accept_index (int32 per harness)
    const float* src = (const float*)d_in[1];   // out_cache_loc
    float*       out = (float*)d_out;

    unsigned long long* state = (unsigned long long*)d_ws;  // NB2 x u64 = 16 KB

    k_init   <<<NB2 / 256, 256, 0, stream>>>(state);
    k_compact<<<NB2, BLOCK, 0, stream>>>(idx, src, out, state);
}